// Round 9
// baseline (207.836 us; speedup 1.0000x reference)
//
#include <hip/hip_runtime.h>
#include <math.h>

#define HW1 (1024 * 1024)
#define WID 1024
#define HEI 1024
#define NMAIN 1024
#define NBLK 1792

typedef float f32x4 __attribute__((ext_vector_type(4)));

// Block-level reduce (wave shfl + LDS) then one atomicAdd per block.
__device__ __forceinline__ void block_atomic_add(float v, float* target, volatile float* sdata) {
#pragma unroll
    for (int off = 32; off > 0; off >>= 1)
        v += __shfl_down(v, off, 64);
    const int lane = threadIdx.x & 63;
    const int wv   = threadIdx.x >> 6;
    if (lane == 0) sdata[wv] = v;
    __syncthreads();
    if (threadIdx.x == 0) {
        float s = 0.f;
        for (int i = 0; i < 4; ++i) s += sdata[i];
        atomicAdd(target, s);
    }
    __syncthreads();
}

// ONE kernel.
// Blocks [0,1024): main (round-2 structure): block=(gy,chunk) owns 64 pool cells
//   + 2 ghost cells -> r_loss, c_loss, and p_loss entirely in-block (no pool buf).
// Blocks [1024,1792): Sobel on batch-0, block=(c,qy) XCD-swizzled so its rows'
//   main block is on the same XCD (L2 reuse of the 25 MB re-read).
// Last block combines acc[] -> out[0].
__global__ __launch_bounds__(256) void k_all(const float* __restrict__ A,
                                             const float* __restrict__ B,
                                             float* __restrict__ acc,
                                             float* __restrict__ out) {
    __shared__ float pd_lds[24 * 4 * 66];   // [plane][yl][66]: slot 0 / 65 = ghosts
    __shared__ float sred[4];

    const int tid = threadIdx.x;

    if (blockIdx.x < NMAIN) {
        // ---------------- main path ----------------
        const int gy    = blockIdx.x >> 2;
        const int chunk = blockIdx.x & 3;
        const int xl    = tid & 63;
        const int yl    = tid >> 6;
        const int gx    = chunk * 64 + xl;     // pool-x == float4 col
        const int y     = gy * 4 + yl;
        const int rowq  = y * 256 + gx;        // float4 index within a plane

        const bool lg = (xl == 0);             // left-ghost owner
        const bool rg = (xl == 63);            // right-ghost owner
        const bool gvalid = (lg && chunk > 0) || (rg && chunk < 3);
        const int  goff   = lg ? -1 : 1;       // ghost cell offset in float4 cols

        const f32x4* A4 = reinterpret_cast<const f32x4*>(A);
        const f32x4* B4 = reinterpret_cast<const f32x4*>(B);

        float na2[12], nb2[12], dt[12];
#pragma unroll
        for (int i = 0; i < 12; ++i) { na2[i] = 0.f; nb2[i] = 0.f; dt[i] = 0.f; }
        float r_sum = 0.f;

#pragma unroll 2
        for (int b = 0; b < 8; ++b) {
#pragma unroll
            for (int c = 0; c < 3; ++c) {
                const int plane = b * 3 + c;
                const int pidx  = plane * (HW1 / 4) + rowq;
                const f32x4 a4 = A4[pidx];
                const f32x4 b4 = B4[pidx];
                float pd = 0.f;
#pragma unroll
                for (int j = 0; j < 4; ++j) {
                    const float a = a4[j], t = b4[j];
                    na2[c * 4 + j] += a * a; nb2[c * 4 + j] += t * t; dt[c * 4 + j] += a * t;
                    r_sum += fabsf(a - t); pd += t - a;
                }
                pd_lds[(plane * 4 + yl) * 66 + 1 + xl] = pd;
                if (lg || rg) {                       // ghost cell (pad -> 0)
                    float pg = 0.f;
                    if (gvalid) {
                        const f32x4 ga = A4[pidx + goff];
                        const f32x4 gb = B4[pidx + goff];
#pragma unroll
                        for (int j = 0; j < 4; ++j) pg += gb[j] - ga[j];
                    }
                    pd_lds[(plane * 4 + yl) * 66 + (lg ? 0 : 65)] = pg;
                }
            }
        }

        // c_loss for this thread's 4 pixels (channels all thread-local)
        float c_sum = 0.f;
#pragma unroll
        for (int j = 0; j < 4; ++j) {
            float cs = 0.f;
#pragma unroll
            for (int c = 0; c < 3; ++c) {
                const float na = fmaxf(sqrtf(na2[c * 4 + j]), 1e-12f);
                const float nb = fmaxf(sqrtf(nb2[c * 4 + j]), 1e-12f);
                cs += dt[c * 4 + j] / (na * nb);
            }
            cs = fminf(fmaxf(cs, -1.0f + 1e-7f), 1.0f - 1e-7f);
            c_sum += acosf(cs);
        }

        __syncthreads();

        // p_loss in-block: 8 b x 64 cells = 512 items, 2 per thread.
        // pd_lds holds 16x pool values; fold /16^2 into 1/256.
        float p_sum = 0.f;
#pragma unroll
        for (int i = 0; i < 2; ++i) {
            const int item = i * 256 + tid;
            const int b    = item >> 6;
            const int x    = item & 63;      // local cell, LDS col 1+x
            const float* pR = pd_lds + ((b * 3 + 0) * 4) * 66;
            const float* pG = pd_lds + ((b * 3 + 1) * 4) * 66;
            const float* pB = pd_lds + ((b * 3 + 2) * 4) * 66;
            float g = 0.f, gl = 0.f, gr = 0.f, rr = 0.f, bb = 0.f;
#pragma unroll
            for (int yy = 0; yy < 4; ++yy) {
                g  += pG[yy * 66 + 1 + x];
                gl += pG[yy * 66 + x];
                gr += pG[yy * 66 + 2 + x];
                rr += pR[yy * 66 + 1 + x];
                bb += pB[yy * 66 + 1 + x];
            }
            const float d0 = g - gl;
            const float d1 = g - gr;
            const float d2 = g - rr;
            const float d3 = g - bb;
            p_sum += d0 * d0 + d1 * d1 + d2 * d2 + d3 * d3;
        }
        p_sum *= (1.0f / 256.0f);

        block_atomic_add(r_sum, acc + 0, sred);
        block_atomic_add(c_sum, acc + 1, sred);
        block_atomic_add(p_sum, acc + 3, sred);
    } else {
        // ---------------- Sobel path: block=(c,qy), 4x4 tile per thread ----------------
        const int k   = blockIdx.x - NMAIN;     // XCD-matched swizzle decode
        const int x8  = k & 7;
        const int m   = k >> 3;
        const int c   = m % 3;
        const int qy  = (m / 3) * 8 + (((x8 & 3) << 1) | (x8 >> 2));
        const int qx  = tid;
        const int x0  = qx * 4;
        const int y0  = qy * 4;

        const float* Ap = A + (size_t)c * HW1;
        const float* Bp = B + (size_t)c * HW1;

        float rd[6][4];  // rowdiff(y,x) = d(y,x-1) - d(y,x+1), rows y0-1..y0+4
#pragma unroll
        for (int r = 0; r < 6; ++r) {
            const int yy = y0 - 1 + r;
            if (yy < 0 || yy >= HEI) {
                rd[r][0] = rd[r][1] = rd[r][2] = rd[r][3] = 0.f;
                continue;
            }
            const float* ap = Ap + (size_t)yy * WID;
            const float* bp = Bp + (size_t)yy * WID;
            const float4 a4 = *reinterpret_cast<const float4*>(ap + x0);
            const float4 b4 = *reinterpret_cast<const float4*>(bp + x0);
            const float dm = (qx > 0)   ? (ap[x0 - 1] - bp[x0 - 1]) : 0.f;
            const float dp = (qx < 255) ? (ap[x0 + 4] - bp[x0 + 4]) : 0.f;
            const float d0 = a4.x - b4.x;
            const float d1 = a4.y - b4.y;
            const float d2 = a4.z - b4.z;
            const float d3 = a4.w - b4.w;
            rd[r][0] = dm - d1;
            rd[r][1] = d0 - d2;
            rd[r][2] = d1 - d3;
            rd[r][3] = d2 - dp;
        }

        float s_sum = 0.f;
#pragma unroll
        for (int o = 0; o < 4; ++o)
#pragma unroll
            for (int i = 0; i < 4; ++i)
                s_sum += fabsf(rd[o][i] + 2.f * rd[o + 1][i] + rd[o + 2][i]);

        block_atomic_add(s_sum, acc + 2, sred);
    }

    // ---------------- completion: last block combines ----------------
    __shared__ unsigned done_rank;
    __threadfence();
    if (tid == 0)
        done_rank = atomicAdd(reinterpret_cast<unsigned*>(acc + 8), 1u);
    __syncthreads();
    if (done_rank == NBLK - 1 && tid == 0) {
        __threadfence();
        const float r = acc[0] * (1.0f / 25165824.0f);  // mean over 8*3*1024*1024
        const float c = acc[1];
        const float s = acc[2];
        const float p = acc[3] * (1.0f / 524288.0f);    // mean over 8*256*256
        out[0] = 0.5f * c + 1.0f * r + 1.0f * p + 0.1f * s;
    }
}

extern "C" void kernel_launch(void* const* d_in, const int* in_sizes, int n_in,
                              void* d_out, int out_size, void* d_ws, size_t ws_size,
                              hipStream_t stream) {
    const float* A = (const float*)d_in[0];  // predictions
    const float* B = (const float*)d_in[1];  // targets
    float* acc = (float*)d_ws;               // acc[0..3] sums, acc[8] counter

    hipMemsetAsync(acc, 0, 64 * sizeof(float), stream);
    hipLaunchKernelGGL(k_all, dim3(NBLK), dim3(256), 0, stream, A, B, acc, (float*)d_out);
}